// Round 6
// baseline (621.373 us; speedup 1.0000x reference)
//
#include <hip/hip_runtime.h>
#include <hip/hip_bf16.h>
#include <math.h>

#define BB 2
#define AA 120000
#define CC 80
#define K_PRE 500
#define MAX_DET 300
#define CAP 2048
#define NBINS 128
#define HB 240                        // hist/gather blocks (120 per image)
#define QTOT (BB * AA * 20)           // 4,800,000 float4 quads
#define QPB (QTOT / HB)               // 20,000 quads per block

// ---------------- workspace layout (bytes) ----------------
// boxes : BB*AA*4 f32            @ 0          3,840,000
// valid : BB*AA u8               @ 3,840,000    240,000
// hist  : BB*CC*NBINS u32        @ 4,080,000     81,920
// cnt   : BB*CC u32              @ 4,161,920        640
// cutbin: BB*CC i32              @ 4,162,560        640
// cand  : BB*CC*CAP u64          @ 4,163,200  2,621,440
#define OFF_BOXES   0
#define OFF_VALID   3840000
#define OFF_HIST    4080000
#define OFF_CNT     4161920
#define OFF_CUT     4162560
#define OFF_CAND    4163200
#define ZERO_WORDS  20640   // hist (20480 w) + cnt (160 w), contiguous

// ---------------- K1: decode + clip + valid, zero hist/cnt ----------------
__global__ __launch_bounds__(256) void k_decode(
    const float* __restrict__ deltas, const float* __restrict__ anchors,
    const int* __restrict__ ih, const int* __restrict__ iw,
    float* __restrict__ boxes, unsigned char* __restrict__ valid,
    unsigned int* __restrict__ zero_base)
{
    int tid = blockIdx.x * 256 + threadIdx.x;
    if (tid < ZERO_WORDS) zero_base[tid] = 0u;
    if (tid >= BB * AA) return;

    float4 d  = ((const float4*)deltas)[tid];
    float4 an = ((const float4*)anchors)[tid];

    const float CLAMPF = (float)4.135166556742356;  // float(log(1000/16))
    double W = (double)(*iw);
    double H = (double)(*ih);

    double aw  = (double)an.z - (double)an.x;
    double ah  = (double)an.w - (double)an.y;
    double acx = (double)an.x + 0.5 * aw;
    double acy = (double)an.y + 0.5 * ah;

    double dw = fmin((double)d.z, (double)CLAMPF);
    double dh = fmin((double)d.w, (double)CLAMPF);

    double pcx = (double)d.x * aw + acx;
    double pcy = (double)d.y * ah + acy;
    double pw  = exp(dw) * aw;
    double ph  = exp(dh) * ah;

    float x1 = (float)fmin(fmax(pcx - 0.5 * pw, 0.0), W);
    float y1 = (float)fmin(fmax(pcy - 0.5 * ph, 0.0), H);
    float x2 = (float)fmin(fmax(pcx + 0.5 * pw, 0.0), W);
    float y2 = (float)fmin(fmax(pcy + 0.5 * ph, 0.0), H);

    float4 bb; bb.x = x1; bb.y = y1; bb.z = x2; bb.w = y2;
    ((float4*)boxes)[tid] = bb;
    valid[tid] = (((x2 - x1) >= 0.01f) && ((y2 - y1) >= 0.01f)) ? 1 : 0;
}

// ---------------- K2: coalesced score histogram ----------------
// Flat float4 walk over scores: lane i reads s4[base+i] (1 KB/wave/inst).
// quad q = idx%20 (classes 4q..4q+3), global anchor ga = idx/20.
// LDS: all 80 classes x 128 bins = 40 KB -> 4 blocks/CU.
__global__ __launch_bounds__(256) void k_hist(
    const float* __restrict__ scores, const unsigned char* __restrict__ valid,
    unsigned int* __restrict__ hist)
{
    __shared__ unsigned int lh[CC * NBINS];   // 40 KB

    int blk   = blockIdx.x;
    int b     = blk / (HB / BB);              // blocks never span images (QPB*120 = AA*20)
    int start = blk * QPB;
    int end   = start + QPB;

    for (int i = threadIdx.x; i < CC * NBINS; i += 256) lh[i] = 0u;
    __syncthreads();

    const float4* s4 = (const float4*)scores;

    #define HPROC(IDX, S)                                                           \
        {                                                                           \
            int q_  = (IDX) % 20;                                                   \
            int ga_ = (IDX) / 20;                                                   \
            if (valid[ga_]) {                                                       \
                unsigned int* lb = &lh[(4 * q_) * NBINS];                           \
                if (S.x > 0.05f) atomicAdd(&lb[0 * NBINS + min((int)(S.x * 128.0f), 127)], 1u); \
                if (S.y > 0.05f) atomicAdd(&lb[1 * NBINS + min((int)(S.y * 128.0f), 127)], 1u); \
                if (S.z > 0.05f) atomicAdd(&lb[2 * NBINS + min((int)(S.z * 128.0f), 127)], 1u); \
                if (S.w > 0.05f) atomicAdd(&lb[3 * NBINS + min((int)(S.w * 128.0f), 127)], 1u); \
            }                                                                       \
        }

    for (int idx = start + threadIdx.x; idx < end; idx += 512) {
        float4 s0 = s4[idx];
        int idx1 = idx + 256;
        bool has1 = idx1 < end;
        float4 s1 = has1 ? s4[idx1] : make_float4(0.f, 0.f, 0.f, 0.f);
        HPROC(idx, s0)
        if (has1) HPROC(idx1, s1)
    }
    #undef HPROC
    __syncthreads();

    unsigned int* gh = hist + (size_t)b * CC * NBINS;
    for (int i = threadIdx.x; i < CC * NBINS; i += 256) {
        unsigned int v = lh[i];
        if (v) atomicAdd(&gh[i], v);
    }
}

// ---------------- K3: find cut bin per (b,c) ----------------
__global__ __launch_bounds__(NBINS) void k_cut(
    const unsigned int* __restrict__ hist, int* __restrict__ cutbin)
{
    __shared__ unsigned int h[NBINS];
    __shared__ int best;
    int bc = blockIdx.x;
    int t  = threadIdx.x;
    h[t] = hist[(size_t)bc * NBINS + t];
    if (t == 0) best = 0;
    __syncthreads();
    unsigned int s = 0;
    for (int j = t; j < NBINS; ++j) s += h[j];   // suffix sum at t
    if (s >= K_PRE) atomicMax(&best, t);
    __syncthreads();
    if (t == 0) cutbin[bc] = best;
}

// ---------------- K4: coalesced candidate gather ----------------
__global__ __launch_bounds__(256) void k_gather(
    const float* __restrict__ scores, const unsigned char* __restrict__ valid,
    const int* __restrict__ cutbin, unsigned int* __restrict__ cnt,
    unsigned long long* __restrict__ cand)
{
    __shared__ int lcut[CC];

    int blk   = blockIdx.x;
    int b     = blk / (HB / BB);
    int start = blk * QPB;
    int end   = start + QPB;

    if (threadIdx.x < CC) lcut[threadIdx.x] = cutbin[b * CC + threadIdx.x];
    __syncthreads();

    const float4* s4 = (const float4*)scores;

    for (int idx = start + threadIdx.x; idx < end; idx += 512) {
        float4 s0 = s4[idx];
        int idx1 = idx + 256;
        bool has1 = idx1 < end;
        float4 s1 = has1 ? s4[idx1] : make_float4(0.f, 0.f, 0.f, 0.f);

        for (int u = 0; u < 2; ++u) {
            if (u && !has1) break;
            int   IDX = u ? idx1 : idx;
            float4 S  = u ? s1 : s0;
            int q_  = IDX % 20;
            int ga_ = IDX / 20;
            if (!valid[ga_]) continue;
            unsigned int a_ = (unsigned int)(ga_ - b * AA);
            unsigned long long lokey = (unsigned long long)(~a_);
            int c0_ = 4 * q_;
            float cv[4] = {S.x, S.y, S.z, S.w};
            #pragma unroll
            for (int cl = 0; cl < 4; ++cl) {
                float sc = cv[cl];
                if (sc > 0.05f) {
                    int bn = min((int)(sc * 128.0f), 127);
                    if (bn >= lcut[c0_ + cl]) {
                        unsigned int pos = atomicAdd(&cnt[b * CC + c0_ + cl], 1u);
                        if (pos < CAP)
                            cand[((size_t)(b * CC + c0_ + cl)) * CAP + pos] =
                                (((unsigned long long)__float_as_uint(sc)) << 32) | lokey;
                    }
                }
            }
        }
    }
}

// ---------------- K5: sort + NMS + compact + write ----------------
// 1024 threads (16 waves). LDS ~60 KB.
// NOTE: sup[i*8 + w] is only WRITTEN for w >= (i>>6) (triangular skip in the
// mask phase). All readers MUST treat w < (i>>6) as zero — those bits are
// j < i and sup rows only suppress j > i.
__global__ __launch_bounds__(1024) void k_nms(
    const float* __restrict__ boxes, const unsigned int* __restrict__ cnt,
    const unsigned long long* __restrict__ cand, float* __restrict__ out)
{
    __shared__ unsigned long long keys[CAP];        // 16 KB
    __shared__ float4 box4[512];                    // 8 KB
    __shared__ float ar[512], scs[512];             // 4 KB
    __shared__ unsigned long long sup[512 * 8];     // 32 KB
    __shared__ unsigned long long keepsh[8];
    __shared__ int pfx[9];

    int bc = blockIdx.x;
    int b  = bc / CC;
    int n  = (int)min(cnt[bc], (unsigned int)CAP);
    int SS = (n > 1024) ? 2048 : 1024;              // adaptive sort size

    const unsigned long long* cp = cand + (size_t)bc * CAP;
    for (int i = threadIdx.x; i < SS; i += 1024)
        keys[i] = (i < n) ? cp[i] : 0ull;

    // bitonic sort, descending
    for (unsigned int k = 2; k <= (unsigned int)SS; k <<= 1) {
        for (unsigned int j = k >> 1; j > 0; j >>= 1) {
            __syncthreads();
            for (unsigned int i = threadIdx.x; i < (unsigned int)SS; i += 1024) {
                unsigned int ixj = i ^ j;
                if (ixj > i) {
                    unsigned long long a = keys[i], bk = keys[ixj];
                    bool up = ((i & k) == 0);
                    if (up ? (a < bk) : (a > bk)) { keys[i] = bk; keys[ixj] = a; }
                }
            }
        }
    }
    __syncthreads();

    // extract top-512, gather boxes
    if (threadIdx.x < 512) {
        int i = threadIdx.x;
        unsigned long long key = keys[i];
        bool v = (key != 0ull);
        scs[i] = v ? __uint_as_float((unsigned int)(key >> 32)) : -1.0f;
        int a = v ? (int)(~(unsigned int)key) : 0;
        float4 bb = make_float4(0.f, 0.f, 0.f, 0.f);
        if (v && i < K_PRE) bb = ((const float4*)boxes)[(size_t)b * AA + a];
        box4[i] = bb;
        ar[i] = (bb.z - bb.x) * (bb.w - bb.y);
    }
    __syncthreads();

    // suppression bitmasks: wave per i (16 waves), ballot over j; triangular skip
    {
        int wave = threadIdx.x >> 6;
        int lane = threadIdx.x & 63;
        for (int i = wave; i < K_PRE; i += 16) {
            float4 bi = box4[i];
            float ia = ar[i];
            for (int jb = (i >> 6); jb < 8; ++jb) {
                int j = jb * 64 + lane;
                bool p = false;
                if (j < K_PRE && j > i) {
                    float4 bj = box4[j];
                    float ltx = fmaxf(bi.x, bj.x);
                    float lty = fmaxf(bi.y, bj.y);
                    float rbx = fminf(bi.z, bj.z);
                    float rby = fminf(bi.w, bj.w);
                    float wx = fmaxf(rbx - ltx, 0.0f);
                    float wy = fmaxf(rby - lty, 0.0f);
                    float inter = wx * wy;
                    float iou = inter / fmaxf(ia + ar[j] - inter, 1e-9f);
                    p = iou > 0.5f;
                }
                unsigned long long m = __ballot(p);
                if (lane == 0) sup[i * 8 + jb] = m;
            }
        }
    }
    __syncthreads();

    // greedy NMS: wave 0, lanes 0-7 own keep words; speculative row prefetch.
    // Row reads are masked: word `lane` of row i is only valid for
    // lane >= (i>>6) (triangular sup fill); below that it's garbage -> use 0.
    if (threadIdx.x < 64) {
        int lane = threadIdx.x;
        bool owner = lane < 8;
        int nv = min(n, K_PRE);
        unsigned long long word = 0ull;
        if (owner) {
            int lo = lane << 6;
            word = (nv >= lo + 64) ? ~0ull
                 : ((nv > lo) ? ((1ull << (nv - lo)) - 1ull) : 0ull);
        }
        unsigned long long sword = word;   // search mask (bits ≤ current cleared)

        #define FINDNEXT(dst)                                                        \
            {                                                                        \
                int c_ = (owner && sword) ? ((lane << 6) + __ffsll((long long)sword) - 1) : 4096; \
                c_ = min(c_, __shfl_xor(c_, 4));                                     \
                c_ = min(c_, __shfl_xor(c_, 2));                                     \
                c_ = min(c_, __shfl_xor(c_, 1));                                     \
                dst = __shfl(c_, 0);                                                 \
            }
        #define CLEAR_LE(ii)                                                         \
            if (lane == ((ii) >> 6)) sword &= ~((2ull << ((ii) & 63)) - 1ull);
        #define ROWLOAD(ii) ((owner && lane >= ((ii) >> 6)) ? sup[((ii) << 3) + lane] : 0ull)

        int i1; FINDNEXT(i1);
        unsigned long long row1 = 0ull;
        if (i1 < 4096) { CLEAR_LE(i1); row1 = ROWLOAD(i1); }
        while (i1 < 4096) {
            int i2; FINDNEXT(i2);                 // speculative: before row1 applied
            unsigned long long row2 = (i2 < 4096) ? ROWLOAD(i2) : 0ull;
            if (owner) { word &= ~row1; sword &= ~row1; }
            if (i2 < 4096) {
                int bitv = (int)((sword >> (i2 & 63)) & 1ull);
                int alive = __shfl(bitv, i2 >> 6);
                if (alive) { CLEAR_LE(i2); i1 = i2; row1 = row2; continue; }
            }
            FINDNEXT(i1);
            row1 = 0ull;
            if (i1 < 4096) { CLEAR_LE(i1); row1 = ROWLOAD(i1); }
        }
        if (owner) keepsh[lane] = word;
        #undef FINDNEXT
        #undef CLEAR_LE
        #undef ROWLOAD
    }
    __syncthreads();

    if (threadIdx.x == 0) {
        int s = 0;
        for (int w = 0; w < 8; ++w) { pfx[w] = s; s += __popcll(keepsh[w]); }
        pfx[8] = s;
    }
    __syncthreads();

    // compaction: kept first (score order), then non-kept (score order)
    int total_kept = pfx[8];
    if (threadIdx.x < K_PRE) {
        int i = threadIdx.x;
        int w = i >> 6, bit = i & 63;
        unsigned long long kw = keepsh[w];
        bool kv = (kw >> bit) & 1ull;
        int kb = pfx[w] + __popcll(kw & ((bit == 0) ? 0ull : ((1ull << bit) - 1ull)));
        int p = kv ? kb : (total_kept + (i - kb));
        if (p < MAX_DET) {
            float* o = out + ((size_t)bc * MAX_DET + p) * 5;
            if (kv) {
                float4 bb = box4[i];
                o[0] = bb.x; o[1] = bb.y; o[2] = bb.z; o[3] = bb.w; o[4] = scs[i];
            } else {
                o[0] = 0.f; o[1] = 0.f; o[2] = 0.f; o[3] = 0.f; o[4] = -1.0f;
            }
        }
    }
}

extern "C" void kernel_launch(void* const* d_in, const int* in_sizes, int n_in,
                              void* d_out, int out_size, void* d_ws, size_t ws_size,
                              hipStream_t stream)
{
    const float* deltas  = (const float*)d_in[0];
    const float* scores  = (const float*)d_in[1];
    const float* anchors = (const float*)d_in[2];
    const int*   ih      = (const int*)d_in[3];
    const int*   iw      = (const int*)d_in[4];
    float* out = (float*)d_out;

    char* w = (char*)d_ws;
    float*              boxes  = (float*)(w + OFF_BOXES);
    unsigned char*      valid  = (unsigned char*)(w + OFF_VALID);
    unsigned int*       hist   = (unsigned int*)(w + OFF_HIST);
    unsigned int*       cnt    = (unsigned int*)(w + OFF_CNT);
    int*                cutbin = (int*)(w + OFF_CUT);
    unsigned long long* cand   = (unsigned long long*)(w + OFF_CAND);

    int g1 = (BB * AA + 255) / 256;
    k_decode<<<g1, 256, 0, stream>>>(deltas, anchors, ih, iw, boxes, valid, hist);
    k_hist<<<HB, 256, 0, stream>>>(scores, valid, hist);
    k_cut<<<BB * CC, NBINS, 0, stream>>>(hist, cutbin);
    k_gather<<<HB, 256, 0, stream>>>(scores, valid, cutbin, cnt, cand);
    k_nms<<<BB * CC, 1024, 0, stream>>>(boxes, cnt, cand, out);
}

// Round 7
// 349.216 us; speedup vs baseline: 1.7793x; 1.7793x over previous
//
#include <hip/hip_runtime.h>
#include <hip/hip_bf16.h>
#include <math.h>

#define BB 2
#define AA 120000
#define CC 80
#define K_PRE 500
#define MAX_DET 300
#define CAP 2048
#define NBINS 128
#define HB 480                        // hist/gather blocks (240 per image)
#define QTOT (BB * AA * 20)           // 4,800,000 float4 quads
#define QPB (QTOT / HB)               // 10,000 quads per block
#define LBUF 3072                     // per-block LDS candidate buffer

// ---------------- workspace layout (bytes) ----------------
#define OFF_BOXES   0
#define OFF_VALID   3840000
#define OFF_HIST    4080000
#define OFF_CNT     4161920
#define OFF_CUT     4162560
#define OFF_CAND    4163200
#define ZERO_WORDS  20640   // hist (20480 w) + cnt (160 w), contiguous

// ---------------- K1: decode + clip + valid, zero hist/cnt ----------------
__global__ __launch_bounds__(256) void k_decode(
    const float* __restrict__ deltas, const float* __restrict__ anchors,
    const int* __restrict__ ih, const int* __restrict__ iw,
    float* __restrict__ boxes, unsigned char* __restrict__ valid,
    unsigned int* __restrict__ zero_base)
{
    int tid = blockIdx.x * 256 + threadIdx.x;
    if (tid < ZERO_WORDS) zero_base[tid] = 0u;
    if (tid >= BB * AA) return;

    float4 d  = ((const float4*)deltas)[tid];
    float4 an = ((const float4*)anchors)[tid];

    const float CLAMPF = (float)4.135166556742356;  // float(log(1000/16))
    double W = (double)(*iw);
    double H = (double)(*ih);

    double aw  = (double)an.z - (double)an.x;
    double ah  = (double)an.w - (double)an.y;
    double acx = (double)an.x + 0.5 * aw;
    double acy = (double)an.y + 0.5 * ah;

    double dw = fmin((double)d.z, (double)CLAMPF);
    double dh = fmin((double)d.w, (double)CLAMPF);

    double pcx = (double)d.x * aw + acx;
    double pcy = (double)d.y * ah + acy;
    double pw  = exp(dw) * aw;
    double ph  = exp(dh) * ah;

    float x1 = (float)fmin(fmax(pcx - 0.5 * pw, 0.0), W);
    float y1 = (float)fmin(fmax(pcy - 0.5 * ph, 0.0), H);
    float x2 = (float)fmin(fmax(pcx + 0.5 * pw, 0.0), W);
    float y2 = (float)fmin(fmax(pcy + 0.5 * ph, 0.0), H);

    float4 bb; bb.x = x1; bb.y = y1; bb.z = x2; bb.w = y2;
    ((float4*)boxes)[tid] = bb;
    valid[tid] = (((x2 - x1) >= 0.01f) && ((y2 - y1) >= 0.01f)) ? 1 : 0;
}

// ---------------- K2: coalesced score histogram, 4-deep MLP ----------------
// Flat float4 walk: lane reads s4[i], s4[i+256], s4[i+512], s4[i+768].
// LDS: 80 classes x 128 bins = 40 KB. Global merge: fire-and-forget atomics.
__global__ __launch_bounds__(256) void k_hist(
    const float* __restrict__ scores, const unsigned char* __restrict__ valid,
    unsigned int* __restrict__ hist)
{
    __shared__ unsigned int lh[CC * NBINS];   // 40 KB

    int blk   = blockIdx.x;
    int b     = blk / (HB / BB);              // 240 blocks per image, never span
    int start = blk * QPB;
    int end   = start + QPB;

    for (int i = threadIdx.x; i < CC * NBINS; i += 256) lh[i] = 0u;
    __syncthreads();

    const float4* s4 = (const float4*)scores;

    for (int i0 = start + threadIdx.x; i0 < end; i0 += 1024) {
        int   ids[4];
        bool  has[4];
        float4 s[4];
        unsigned char vs[4];
        #pragma unroll
        for (int u = 0; u < 4; ++u) {
            int id = i0 + u * 256;
            has[u] = id < end;
            ids[u] = has[u] ? id : start;
        }
        #pragma unroll
        for (int u = 0; u < 4; ++u) s[u] = s4[ids[u]];
        #pragma unroll
        for (int u = 0; u < 4; ++u) vs[u] = valid[ids[u] / 20];
        #pragma unroll
        for (int u = 0; u < 4; ++u) {
            if (has[u] && vs[u]) {
                int q = ids[u] % 20;
                unsigned int* lb = &lh[(4 * q) * NBINS];
                float4 S = s[u];
                if (S.x > 0.05f) atomicAdd(&lb[0 * NBINS + min((int)(S.x * 128.0f), 127)], 1u);
                if (S.y > 0.05f) atomicAdd(&lb[1 * NBINS + min((int)(S.y * 128.0f), 127)], 1u);
                if (S.z > 0.05f) atomicAdd(&lb[2 * NBINS + min((int)(S.z * 128.0f), 127)], 1u);
                if (S.w > 0.05f) atomicAdd(&lb[3 * NBINS + min((int)(S.w * 128.0f), 127)], 1u);
            }
        }
    }
    __syncthreads();

    unsigned int* gh = hist + (size_t)b * CC * NBINS;
    for (int i = threadIdx.x; i < CC * NBINS; i += 256) {
        unsigned int v = lh[i];
        if (v) atomicAdd(&gh[i], v);   // no return value -> no wave stall
    }
}

// ---------------- K3: find cut bin per (b,c) ----------------
__global__ __launch_bounds__(NBINS) void k_cut(
    const unsigned int* __restrict__ hist, int* __restrict__ cutbin)
{
    __shared__ unsigned int h[NBINS];
    __shared__ int best;
    int bc = blockIdx.x;
    int t  = threadIdx.x;
    h[t] = hist[(size_t)bc * NBINS + t];
    if (t == 0) best = 0;
    __syncthreads();
    unsigned int s = 0;
    for (int j = t; j < NBINS; ++j) s += h[j];   // suffix sum at t
    if (s >= K_PRE) atomicMax(&best, t);
    __syncthreads();
    if (t == 0) cutbin[bc] = best;
}

// ---------------- K4: gather with LDS staging + block-level reservation ----
// Per-candidate work is LDS-only; ONE global atomicAdd per (block,class)
// reserves the cand[] range; scatter from LDS afterwards. Order within a
// class is racy but k_nms sorts on the full key -> deterministic output.
__global__ __launch_bounds__(256) void k_gather(
    const float* __restrict__ scores, const unsigned char* __restrict__ valid,
    const int* __restrict__ cutbin, unsigned int* __restrict__ cnt,
    unsigned long long* __restrict__ cand)
{
    __shared__ int lcut[CC];
    __shared__ unsigned int lcnt[CC];
    __shared__ unsigned int lbase[CC];          // reservation base, then cursor
    __shared__ unsigned long long lkey[LBUF];   // 24 KB
    __shared__ unsigned short lcls[LBUF];       // 6 KB
    __shared__ unsigned int ltot;

    int blk   = blockIdx.x;
    int b     = blk / (HB / BB);
    int start = blk * QPB;
    int end   = start + QPB;

    if (threadIdx.x < CC) {
        lcut[threadIdx.x] = cutbin[b * CC + threadIdx.x];
        lcnt[threadIdx.x] = 0u;
    }
    if (threadIdx.x == 255) ltot = 0u;
    __syncthreads();

    const float4* s4 = (const float4*)scores;

    for (int i0 = start + threadIdx.x; i0 < end; i0 += 1024) {
        int   ids[4];
        bool  has[4];
        float4 s[4];
        unsigned char vs[4];
        #pragma unroll
        for (int u = 0; u < 4; ++u) {
            int id = i0 + u * 256;
            has[u] = id < end;
            ids[u] = has[u] ? id : start;
        }
        #pragma unroll
        for (int u = 0; u < 4; ++u) s[u] = s4[ids[u]];
        #pragma unroll
        for (int u = 0; u < 4; ++u) vs[u] = valid[ids[u] / 20];
        #pragma unroll
        for (int u = 0; u < 4; ++u) {
            if (has[u] && vs[u]) {
                int ga = ids[u] / 20;
                int c0 = 4 * (ids[u] % 20);
                unsigned long long lokey =
                    (unsigned long long)(~(unsigned int)(ga - b * AA));
                float cv[4] = {s[u].x, s[u].y, s[u].z, s[u].w};
                #pragma unroll
                for (int cl = 0; cl < 4; ++cl) {
                    float sc = cv[cl];
                    if (sc > 0.05f) {
                        int bn = min((int)(sc * 128.0f), 127);
                        int c  = c0 + cl;
                        if (bn >= lcut[c]) {
                            unsigned int p = atomicAdd(&ltot, 1u);
                            if (p < LBUF) {
                                lkey[p] = (((unsigned long long)__float_as_uint(sc)) << 32) | lokey;
                                lcls[p] = (unsigned short)c;
                                atomicAdd(&lcnt[c], 1u);
                            }
                        }
                    }
                }
            }
        }
    }
    __syncthreads();

    if (threadIdx.x < CC) {
        unsigned int n = lcnt[threadIdx.x];
        if (n) lbase[threadIdx.x] = atomicAdd(&cnt[b * CC + threadIdx.x], n);
    }
    __syncthreads();

    unsigned int tot = min(ltot, (unsigned int)LBUF);
    for (unsigned int i = threadIdx.x; i < tot; i += 256) {
        int c = lcls[i];
        unsigned int pos = atomicAdd(&lbase[c], 1u);   // cursor from base
        if (pos < CAP)
            cand[((size_t)(b * CC + c)) * CAP + pos] = lkey[i];
    }
}

// ---------------- K5: sort + NMS + compact + write ----------------
// 1024 threads (16 waves). LDS ~60 KB.
// NOTE: sup[i*8 + w] is only WRITTEN for w >= (i>>6) (triangular skip in the
// mask phase). All readers MUST treat w < (i>>6) as zero — those bits are
// j < i and sup rows only suppress j > i.
__global__ __launch_bounds__(1024) void k_nms(
    const float* __restrict__ boxes, const unsigned int* __restrict__ cnt,
    const unsigned long long* __restrict__ cand, float* __restrict__ out)
{
    __shared__ unsigned long long keys[CAP];        // 16 KB
    __shared__ float4 box4[512];                    // 8 KB
    __shared__ float ar[512], scs[512];             // 4 KB
    __shared__ unsigned long long sup[512 * 8];     // 32 KB
    __shared__ unsigned long long keepsh[8];
    __shared__ int pfx[9];

    int bc = blockIdx.x;
    int b  = bc / CC;
    int n  = (int)min(cnt[bc], (unsigned int)CAP);
    int SS = (n > 1024) ? 2048 : 1024;              // adaptive sort size

    const unsigned long long* cp = cand + (size_t)bc * CAP;
    for (int i = threadIdx.x; i < SS; i += 1024)
        keys[i] = (i < n) ? cp[i] : 0ull;

    // bitonic sort, descending
    for (unsigned int k = 2; k <= (unsigned int)SS; k <<= 1) {
        for (unsigned int j = k >> 1; j > 0; j >>= 1) {
            __syncthreads();
            for (unsigned int i = threadIdx.x; i < (unsigned int)SS; i += 1024) {
                unsigned int ixj = i ^ j;
                if (ixj > i) {
                    unsigned long long a = keys[i], bk = keys[ixj];
                    bool up = ((i & k) == 0);
                    if (up ? (a < bk) : (a > bk)) { keys[i] = bk; keys[ixj] = a; }
                }
            }
        }
    }
    __syncthreads();

    // extract top-512, gather boxes
    if (threadIdx.x < 512) {
        int i = threadIdx.x;
        unsigned long long key = keys[i];
        bool v = (key != 0ull);
        scs[i] = v ? __uint_as_float((unsigned int)(key >> 32)) : -1.0f;
        int a = v ? (int)(~(unsigned int)key) : 0;
        float4 bb = make_float4(0.f, 0.f, 0.f, 0.f);
        if (v && i < K_PRE) bb = ((const float4*)boxes)[(size_t)b * AA + a];
        box4[i] = bb;
        ar[i] = (bb.z - bb.x) * (bb.w - bb.y);
    }
    __syncthreads();

    // suppression bitmasks: wave per i (16 waves), ballot over j; triangular skip
    {
        int wave = threadIdx.x >> 6;
        int lane = threadIdx.x & 63;
        for (int i = wave; i < K_PRE; i += 16) {
            float4 bi = box4[i];
            float ia = ar[i];
            for (int jb = (i >> 6); jb < 8; ++jb) {
                int j = jb * 64 + lane;
                bool p = false;
                if (j < K_PRE && j > i) {
                    float4 bj = box4[j];
                    float ltx = fmaxf(bi.x, bj.x);
                    float lty = fmaxf(bi.y, bj.y);
                    float rbx = fminf(bi.z, bj.z);
                    float rby = fminf(bi.w, bj.w);
                    float wx = fmaxf(rbx - ltx, 0.0f);
                    float wy = fmaxf(rby - lty, 0.0f);
                    float inter = wx * wy;
                    float iou = inter / fmaxf(ia + ar[j] - inter, 1e-9f);
                    p = iou > 0.5f;
                }
                unsigned long long m = __ballot(p);
                if (lane == 0) sup[i * 8 + jb] = m;
            }
        }
    }
    __syncthreads();

    // greedy NMS: wave 0, lanes 0-7 own keep words; speculative row prefetch.
    if (threadIdx.x < 64) {
        int lane = threadIdx.x;
        bool owner = lane < 8;
        int nv = min(n, K_PRE);
        unsigned long long word = 0ull;
        if (owner) {
            int lo = lane << 6;
            word = (nv >= lo + 64) ? ~0ull
                 : ((nv > lo) ? ((1ull << (nv - lo)) - 1ull) : 0ull);
        }
        unsigned long long sword = word;   // search mask (bits ≤ current cleared)

        #define FINDNEXT(dst)                                                        \
            {                                                                        \
                int c_ = (owner && sword) ? ((lane << 6) + __ffsll((long long)sword) - 1) : 4096; \
                c_ = min(c_, __shfl_xor(c_, 4));                                     \
                c_ = min(c_, __shfl_xor(c_, 2));                                     \
                c_ = min(c_, __shfl_xor(c_, 1));                                     \
                dst = __shfl(c_, 0);                                                 \
            }
        #define CLEAR_LE(ii)                                                         \
            if (lane == ((ii) >> 6)) sword &= ~((2ull << ((ii) & 63)) - 1ull);
        #define ROWLOAD(ii) ((owner && lane >= ((ii) >> 6)) ? sup[((ii) << 3) + lane] : 0ull)

        int i1; FINDNEXT(i1);
        unsigned long long row1 = 0ull;
        if (i1 < 4096) { CLEAR_LE(i1); row1 = ROWLOAD(i1); }
        while (i1 < 4096) {
            int i2; FINDNEXT(i2);                 // speculative: before row1 applied
            unsigned long long row2 = (i2 < 4096) ? ROWLOAD(i2) : 0ull;
            if (owner) { word &= ~row1; sword &= ~row1; }
            if (i2 < 4096) {
                int bitv = (int)((sword >> (i2 & 63)) & 1ull);
                int alive = __shfl(bitv, i2 >> 6);
                if (alive) { CLEAR_LE(i2); i1 = i2; row1 = row2; continue; }
            }
            FINDNEXT(i1);
            row1 = 0ull;
            if (i1 < 4096) { CLEAR_LE(i1); row1 = ROWLOAD(i1); }
        }
        if (owner) keepsh[lane] = word;
        #undef FINDNEXT
        #undef CLEAR_LE
        #undef ROWLOAD
    }
    __syncthreads();

    if (threadIdx.x == 0) {
        int s = 0;
        for (int w = 0; w < 8; ++w) { pfx[w] = s; s += __popcll(keepsh[w]); }
        pfx[8] = s;
    }
    __syncthreads();

    // compaction: kept first (score order), then non-kept (score order)
    int total_kept = pfx[8];
    if (threadIdx.x < K_PRE) {
        int i = threadIdx.x;
        int w = i >> 6, bit = i & 63;
        unsigned long long kw = keepsh[w];
        bool kv = (kw >> bit) & 1ull;
        int kb = pfx[w] + __popcll(kw & ((bit == 0) ? 0ull : ((1ull << bit) - 1ull)));
        int p = kv ? kb : (total_kept + (i - kb));
        if (p < MAX_DET) {
            float* o = out + ((size_t)bc * MAX_DET + p) * 5;
            if (kv) {
                float4 bb = box4[i];
                o[0] = bb.x; o[1] = bb.y; o[2] = bb.z; o[3] = bb.w; o[4] = scs[i];
            } else {
                o[0] = 0.f; o[1] = 0.f; o[2] = 0.f; o[3] = 0.f; o[4] = -1.0f;
            }
        }
    }
}

extern "C" void kernel_launch(void* const* d_in, const int* in_sizes, int n_in,
                              void* d_out, int out_size, void* d_ws, size_t ws_size,
                              hipStream_t stream)
{
    const float* deltas  = (const float*)d_in[0];
    const float* scores  = (const float*)d_in[1];
    const float* anchors = (const float*)d_in[2];
    const int*   ih      = (const int*)d_in[3];
    const int*   iw      = (const int*)d_in[4];
    float* out = (float*)d_out;

    char* w = (char*)d_ws;
    float*              boxes  = (float*)(w + OFF_BOXES);
    unsigned char*      valid  = (unsigned char*)(w + OFF_VALID);
    unsigned int*       hist   = (unsigned int*)(w + OFF_HIST);
    unsigned int*       cnt    = (unsigned int*)(w + OFF_CNT);
    int*                cutbin = (int*)(w + OFF_CUT);
    unsigned long long* cand   = (unsigned long long*)(w + OFF_CAND);

    int g1 = (BB * AA + 255) / 256;
    k_decode<<<g1, 256, 0, stream>>>(deltas, anchors, ih, iw, boxes, valid, hist);
    k_hist<<<HB, 256, 0, stream>>>(scores, valid, hist);
    k_cut<<<BB * CC, NBINS, 0, stream>>>(hist, cutbin);
    k_gather<<<HB, 256, 0, stream>>>(scores, valid, cutbin, cnt, cand);
    k_nms<<<BB * CC, 1024, 0, stream>>>(boxes, cnt, cand, out);
}

// Round 9
// 241.437 us; speedup vs baseline: 2.5736x; 1.4464x over previous
//
#include <hip/hip_runtime.h>
#include <hip/hip_bf16.h>
#include <math.h>

#define BB 2
#define AA 120000
#define CC 80
#define K_PRE 500
#define MAX_DET 300
#define CAP 2048
#define NB2 256                       // score bins (u16-packed, 2 per u32)
#define NBW 128                       // u32 words per class histogram
#define HB 480                        // hist/gather blocks (240 per image)
#define QTOT (BB * AA * 20)           // 4,800,000 float4 quads
#define QPB (QTOT / HB)               // 10,000 quads per block
#define LBUF 3072                     // per-block LDS candidate buffer

// ---------------- workspace layout (bytes) ----------------
#define OFF_BOXES   0
#define OFF_VALID   3840000
#define OFF_HIST    4080000
#define OFF_CNT     4161920
#define OFF_CUT     4162560
#define OFF_CAND    4163200
#define ZERO_WORDS  20640   // hist (BB*CC*NBW = 20480 w) + cnt (160 w), contiguous

// ---------------- K1: decode + clip + valid, zero hist/cnt ----------------
__global__ __launch_bounds__(256) void k_decode(
    const float* __restrict__ deltas, const float* __restrict__ anchors,
    const int* __restrict__ ih, const int* __restrict__ iw,
    float* __restrict__ boxes, unsigned char* __restrict__ valid,
    unsigned int* __restrict__ zero_base)
{
    int tid = blockIdx.x * 256 + threadIdx.x;
    if (tid < ZERO_WORDS) zero_base[tid] = 0u;
    if (tid >= BB * AA) return;

    float4 d  = ((const float4*)deltas)[tid];
    float4 an = ((const float4*)anchors)[tid];

    const float CLAMPF = (float)4.135166556742356;  // float(log(1000/16))
    double W = (double)(*iw);
    double H = (double)(*ih);

    double aw  = (double)an.z - (double)an.x;
    double ah  = (double)an.w - (double)an.y;
    double acx = (double)an.x + 0.5 * aw;
    double acy = (double)an.y + 0.5 * ah;

    double dw = fmin((double)d.z, (double)CLAMPF);
    double dh = fmin((double)d.w, (double)CLAMPF);

    double pcx = (double)d.x * aw + acx;
    double pcy = (double)d.y * ah + acy;
    double pw  = exp(dw) * aw;
    double ph  = exp(dh) * ah;

    float x1 = (float)fmin(fmax(pcx - 0.5 * pw, 0.0), W);
    float y1 = (float)fmin(fmax(pcy - 0.5 * ph, 0.0), H);
    float x2 = (float)fmin(fmax(pcx + 0.5 * pw, 0.0), W);
    float y2 = (float)fmin(fmax(pcy + 0.5 * ph, 0.0), H);

    float4 bb; bb.x = x1; bb.y = y1; bb.z = x2; bb.w = y2;
    ((float4*)boxes)[tid] = bb;
    valid[tid] = (((x2 - x1) >= 0.01f) && ((y2 - y1) >= 0.01f)) ? 1 : 0;
}

// ---------------- K2: coalesced score histogram, 256 bins u16-packed ------
__global__ __launch_bounds__(256) void k_hist(
    const float* __restrict__ scores, const unsigned char* __restrict__ valid,
    unsigned int* __restrict__ hist)
{
    __shared__ unsigned int lh[CC * NBW];   // 40 KB

    int blk   = blockIdx.x;
    int b     = blk / (HB / BB);
    int start = blk * QPB;
    int end   = start + QPB;

    for (int i = threadIdx.x; i < CC * NBW; i += 256) lh[i] = 0u;
    __syncthreads();

    const float4* s4 = (const float4*)scores;

    for (int i0 = start + threadIdx.x; i0 < end; i0 += 1024) {
        int   ids[4];
        bool  has[4];
        float4 s[4];
        unsigned char vs[4];
        #pragma unroll
        for (int u = 0; u < 4; ++u) {
            int id = i0 + u * 256;
            has[u] = id < end;
            ids[u] = has[u] ? id : start;
        }
        #pragma unroll
        for (int u = 0; u < 4; ++u) s[u] = s4[ids[u]];
        #pragma unroll
        for (int u = 0; u < 4; ++u) vs[u] = valid[ids[u] / 20];
        #pragma unroll
        for (int u = 0; u < 4; ++u) {
            if (has[u] && vs[u]) {
                int q = ids[u] % 20;
                unsigned int* lb = &lh[(4 * q) * NBW];
                float cv[4] = {s[u].x, s[u].y, s[u].z, s[u].w};
                #pragma unroll
                for (int cl = 0; cl < 4; ++cl) {
                    float sc = cv[cl];
                    if (sc > 0.05f) {
                        int bn = min((int)(sc * 256.0f), 255);
                        atomicAdd(&lb[cl * NBW + (bn >> 1)], (bn & 1) ? 65536u : 1u);
                    }
                }
            }
        }
    }
    __syncthreads();

    unsigned int* gh = hist + (size_t)b * CC * NBW;
    for (int i = threadIdx.x; i < CC * NBW; i += 256) {
        unsigned int v = lh[i];
        if (v) atomicAdd(&gh[i], v);   // packed halves; totals < 65536 per half
    }
}

// ---------------- K3: find cut bin per (b,c), 256 bins -------------------
__global__ __launch_bounds__(256) void k_cut(
    const unsigned int* __restrict__ hist, int* __restrict__ cutbin)
{
    __shared__ unsigned int hw[NBW];
    __shared__ int best;
    int bc = blockIdx.x;
    int t  = threadIdx.x;
    if (t < NBW) hw[t] = hist[(size_t)bc * NBW + t];
    if (t == 0) best = 0;
    __syncthreads();
    unsigned int s = 0;
    for (int j = t; j < NB2; ++j)
        s += (hw[j >> 1] >> ((j & 1) * 16)) & 0xFFFFu;   // suffix sum at t
    if (s >= K_PRE) atomicMax(&best, t);
    __syncthreads();
    if (t == 0) cutbin[bc] = best;
}

// ---------------- K4: gather with LDS staging + block reservation --------
__global__ __launch_bounds__(256) void k_gather(
    const float* __restrict__ scores, const unsigned char* __restrict__ valid,
    const int* __restrict__ cutbin, unsigned int* __restrict__ cnt,
    unsigned long long* __restrict__ cand)
{
    __shared__ int lcut[CC];
    __shared__ unsigned int lcnt[CC];
    __shared__ unsigned int lbase[CC];
    __shared__ unsigned long long lkey[LBUF];   // 24 KB
    __shared__ unsigned short lcls[LBUF];       // 6 KB
    __shared__ unsigned int ltot;

    int blk   = blockIdx.x;
    int b     = blk / (HB / BB);
    int start = blk * QPB;
    int end   = start + QPB;

    if (threadIdx.x < CC) {
        lcut[threadIdx.x] = cutbin[b * CC + threadIdx.x];
        lcnt[threadIdx.x] = 0u;
    }
    if (threadIdx.x == 255) ltot = 0u;
    __syncthreads();

    const float4* s4 = (const float4*)scores;

    for (int i0 = start + threadIdx.x; i0 < end; i0 += 1024) {
        int   ids[4];
        bool  has[4];
        float4 s[4];
        unsigned char vs[4];
        #pragma unroll
        for (int u = 0; u < 4; ++u) {
            int id = i0 + u * 256;
            has[u] = id < end;
            ids[u] = has[u] ? id : start;
        }
        #pragma unroll
        for (int u = 0; u < 4; ++u) s[u] = s4[ids[u]];
        #pragma unroll
        for (int u = 0; u < 4; ++u) vs[u] = valid[ids[u] / 20];
        #pragma unroll
        for (int u = 0; u < 4; ++u) {
            if (has[u] && vs[u]) {
                int ga = ids[u] / 20;
                int c0 = 4 * (ids[u] % 20);
                unsigned long long lokey =
                    (unsigned long long)(~(unsigned int)(ga - b * AA));
                float cv[4] = {s[u].x, s[u].y, s[u].z, s[u].w};
                #pragma unroll
                for (int cl = 0; cl < 4; ++cl) {
                    float sc = cv[cl];
                    if (sc > 0.05f) {
                        int bn = min((int)(sc * 256.0f), 255);
                        int c  = c0 + cl;
                        if (bn >= lcut[c]) {
                            unsigned int p = atomicAdd(&ltot, 1u);
                            if (p < LBUF) {
                                lkey[p] = (((unsigned long long)__float_as_uint(sc)) << 32) | lokey;
                                lcls[p] = (unsigned short)c;
                                atomicAdd(&lcnt[c], 1u);
                            }
                        }
                    }
                }
            }
        }
    }
    __syncthreads();

    if (threadIdx.x < CC) {
        unsigned int nn = lcnt[threadIdx.x];
        if (nn) lbase[threadIdx.x] = atomicAdd(&cnt[b * CC + threadIdx.x], nn);
    }
    __syncthreads();

    unsigned int tot = min(ltot, (unsigned int)LBUF);
    for (unsigned int i = threadIdx.x; i < tot; i += 256) {
        int c = lcls[i];
        unsigned int pos = atomicAdd(&lbase[c], 1u);
        if (pos < CAP)
            cand[((size_t)(b * CC + c)) * CAP + pos] = lkey[i];
    }
}

// ---------------- K5: sort + NMS (transposed mask, register GS greedy) ----
// supT is FULLY ZEROED before the triangular build: no word can ever be
// read uninitialized. Greedy keeps kept-words in per-lane registers (ballot
// results are wave-uniform) -> no intra-wave LDS write/read hazard.
__global__ __launch_bounds__(1024) void k_nms(
    const float* __restrict__ boxes, const unsigned int* __restrict__ cnt,
    const unsigned long long* __restrict__ cand, float* __restrict__ out)
{
    __shared__ unsigned long long keys[CAP];        // 16 KB
    __shared__ float4 box4[512];                    // 8 KB
    __shared__ float ar[512], scs[512];             // 4 KB
    __shared__ unsigned long long supT[512 * 8];    // 32 KB
    __shared__ unsigned long long keepsh[8];
    __shared__ int pfx[9];

    int bc = blockIdx.x;
    int b  = bc / CC;
    int n  = (int)min(cnt[bc], (unsigned int)CAP);
    int SS = (n > 1024) ? 2048 : 1024;              // 256-bin cut => usually 1024

    const unsigned long long* cp = cand + (size_t)bc * CAP;
    for (int i = threadIdx.x; i < SS; i += 1024)
        keys[i] = (i < n) ? cp[i] : 0ull;

    // bitonic sort, descending
    for (unsigned int k = 2; k <= (unsigned int)SS; k <<= 1) {
        for (unsigned int j = k >> 1; j > 0; j >>= 1) {
            __syncthreads();
            for (unsigned int i = threadIdx.x; i < (unsigned int)SS; i += 1024) {
                unsigned int ixj = i ^ j;
                if (ixj > i) {
                    unsigned long long a = keys[i], bk = keys[ixj];
                    bool up = ((i & k) == 0);
                    if (up ? (a < bk) : (a > bk)) { keys[i] = bk; keys[ixj] = a; }
                }
            }
        }
    }
    __syncthreads();

    // extract top-512, gather boxes
    if (threadIdx.x < 512) {
        int i = threadIdx.x;
        unsigned long long key = keys[i];
        bool v = (key != 0ull);
        scs[i] = v ? __uint_as_float((unsigned int)(key >> 32)) : -1.0f;
        int a = v ? (int)(~(unsigned int)key) : 0;
        float4 bb = make_float4(0.f, 0.f, 0.f, 0.f);
        if (v && i < K_PRE) bb = ((const float4*)boxes)[(size_t)b * AA + a];
        box4[i] = bb;
        ar[i] = (bb.z - bb.x) * (bb.w - bb.y);
    }
    // zero ALL of supT (defensive: no uninitialized reads possible)
    for (int i = threadIdx.x; i < 512 * 8; i += 1024) supT[i] = 0ull;
    __syncthreads();

    int nv = min(n, K_PRE);

    // transposed suppression masks: wave per j, ballot over i (i<j only)
    {
        int wave = threadIdx.x >> 6;
        int lane = threadIdx.x & 63;
        for (int j = wave; j < 512; j += 16) {
            float4 bj = box4[j];
            float ja = ar[j];
            int wj = j >> 6;
            for (int iw = 0; iw <= wj; ++iw) {
                int i = iw * 64 + lane;
                bool p = false;
                if (i < j && j < nv) {
                    float4 bi = box4[i];
                    float ltx = fmaxf(bi.x, bj.x);
                    float lty = fmaxf(bi.y, bj.y);
                    float rbx = fminf(bi.z, bj.z);
                    float rby = fminf(bi.w, bj.w);
                    float wx = fmaxf(rbx - ltx, 0.0f);
                    float wy = fmaxf(rby - lty, 0.0f);
                    float inter = wx * wy;
                    float iou = inter / fmaxf(ar[i] + ja - inter, 1e-9f);
                    p = iou > 0.5f;
                }
                unsigned long long m = __ballot(p);
                if (lane == 0) supT[j * 8 + iw] = m;
            }
        }
    }
    __syncthreads();

    // exact greedy: word-blocked Gauss-Seidel, intra-word bounded Jacobi.
    // kept[] lives in registers (wave-uniform ballot values) — no LDS RAW.
    if (threadIdx.x < 64) {
        int l = threadIdx.x;
        unsigned long long kept[8];
        #pragma unroll
        for (int w = 0; w < 8; ++w) {
            int j = w * 64 + l;
            bool vj = j < nv;
            bool ext = false;
            #pragma unroll
            for (int w2 = 0; w2 < 8; ++w2)
                if (w2 < w) ext = ext || ((supT[j * 8 + w2] & kept[w2]) != 0ull);
            unsigned long long intra = supT[j * 8 + w];   // bits i<j only
            bool base = vj && !ext;
            unsigned long long kw = __ballot(base);
            for (int r = 0; r < 64; ++r) {                // depth <= 64 => exact
                bool k2 = base && ((intra & kw) == 0ull);
                unsigned long long nkw = __ballot(k2);
                if (nkw == kw) break;
                kw = nkw;
            }
            kept[w] = kw;
        }
        if (l < 8) keepsh[l] = kept[l];
    }
    __syncthreads();

    if (threadIdx.x == 0) {
        int s = 0;
        for (int w = 0; w < 8; ++w) { pfx[w] = s; s += __popcll(keepsh[w]); }
        pfx[8] = s;
    }
    __syncthreads();

    // compaction: kept first (score order), then non-kept (score order)
    int total_kept = pfx[8];
    if (threadIdx.x < K_PRE) {
        int i = threadIdx.x;
        int w = i >> 6, bit = i & 63;
        unsigned long long kw = keepsh[w];
        bool kv = (kw >> bit) & 1ull;
        int kb = pfx[w] + __popcll(kw & ((bit == 0) ? 0ull : ((1ull << bit) - 1ull)));
        int p = kv ? kb : (total_kept + (i - kb));
        if (p < MAX_DET) {
            float* o = out + ((size_t)bc * MAX_DET + p) * 5;
            if (kv) {
                float4 bb = box4[i];
                o[0] = bb.x; o[1] = bb.y; o[2] = bb.z; o[3] = bb.w; o[4] = scs[i];
            } else {
                o[0] = 0.f; o[1] = 0.f; o[2] = 0.f; o[3] = 0.f; o[4] = -1.0f;
            }
        }
    }
}

extern "C" void kernel_launch(void* const* d_in, const int* in_sizes, int n_in,
                              void* d_out, int out_size, void* d_ws, size_t ws_size,
                              hipStream_t stream)
{
    const float* deltas  = (const float*)d_in[0];
    const float* scores  = (const float*)d_in[1];
    const float* anchors = (const float*)d_in[2];
    const int*   ih      = (const int*)d_in[3];
    const int*   iw      = (const int*)d_in[4];
    float* out = (float*)d_out;

    char* w = (char*)d_ws;
    float*              boxes  = (float*)(w + OFF_BOXES);
    unsigned char*      valid  = (unsigned char*)(w + OFF_VALID);
    unsigned int*       hist   = (unsigned int*)(w + OFF_HIST);
    unsigned int*       cnt    = (unsigned int*)(w + OFF_CNT);
    int*                cutbin = (int*)(w + OFF_CUT);
    unsigned long long* cand   = (unsigned long long*)(w + OFF_CAND);

    int g1 = (BB * AA + 255) / 256;
    k_decode<<<g1, 256, 0, stream>>>(deltas, anchors, ih, iw, boxes, valid, hist);
    k_hist<<<HB, 256, 0, stream>>>(scores, valid, hist);
    k_cut<<<BB * CC, 256, 0, stream>>>(hist, cutbin);
    k_gather<<<HB, 256, 0, stream>>>(scores, valid, cutbin, cnt, cand);
    k_nms<<<BB * CC, 1024, 0, stream>>>(boxes, cnt, cand, out);
}

// Round 10
// 235.948 us; speedup vs baseline: 2.6335x; 1.0233x over previous
//
#include <hip/hip_runtime.h>
#include <hip/hip_bf16.h>
#include <math.h>

#define BB 2
#define AA 120000
#define CC 80
#define K_PRE 500
#define MAX_DET 300
#define CAP 2048
#define NB2 256                       // score bins (u16-packed, 2 per u32)
#define NBW 128                       // u32 words per class histogram
#define HB 960                        // hist/gather blocks (480 per image)
#define QTOT (BB * AA * 20)           // 4,800,000 float4 quads
#define QPB (QTOT / HB)               // 5,000 quads per block
#define LBUF 3072                     // per-block LDS candidate buffer

// ---------------- workspace layout (bytes) ----------------
#define OFF_BOXES   0
#define OFF_VALID   3840000
#define OFF_HIST    4080000
#define OFF_CNT     4161920
#define OFF_CUT     4162560
#define OFF_CAND    4163200
#define ZERO_WORDS  20640   // hist (BB*CC*NBW = 20480 w) + cnt (160 w), contiguous

// ---------------- K1: decode + clip + valid, zero hist/cnt ----------------
__global__ __launch_bounds__(256) void k_decode(
    const float* __restrict__ deltas, const float* __restrict__ anchors,
    const int* __restrict__ ih, const int* __restrict__ iw,
    float* __restrict__ boxes, unsigned char* __restrict__ valid,
    unsigned int* __restrict__ zero_base)
{
    int tid = blockIdx.x * 256 + threadIdx.x;
    if (tid < ZERO_WORDS) zero_base[tid] = 0u;
    if (tid >= BB * AA) return;

    float4 d  = ((const float4*)deltas)[tid];
    float4 an = ((const float4*)anchors)[tid];

    const float CLAMPF = (float)4.135166556742356;  // float(log(1000/16))
    double W = (double)(*iw);
    double H = (double)(*ih);

    double aw  = (double)an.z - (double)an.x;
    double ah  = (double)an.w - (double)an.y;
    double acx = (double)an.x + 0.5 * aw;
    double acy = (double)an.y + 0.5 * ah;

    double dw = fmin((double)d.z, (double)CLAMPF);
    double dh = fmin((double)d.w, (double)CLAMPF);

    double pcx = (double)d.x * aw + acx;
    double pcy = (double)d.y * ah + acy;
    double pw  = exp(dw) * aw;
    double ph  = exp(dh) * ah;

    float x1 = (float)fmin(fmax(pcx - 0.5 * pw, 0.0), W);
    float y1 = (float)fmin(fmax(pcy - 0.5 * ph, 0.0), H);
    float x2 = (float)fmin(fmax(pcx + 0.5 * pw, 0.0), W);
    float y2 = (float)fmin(fmax(pcy + 0.5 * ph, 0.0), H);

    float4 bb; bb.x = x1; bb.y = y1; bb.z = x2; bb.w = y2;
    ((float4*)boxes)[tid] = bb;
    valid[tid] = (((x2 - x1) >= 0.01f) && ((y2 - y1) >= 0.01f)) ? 1 : 0;
}

// ---------------- K2: coalesced score histogram, 256 bins u16-packed ------
__global__ __launch_bounds__(256) void k_hist(
    const float* __restrict__ scores, const unsigned char* __restrict__ valid,
    unsigned int* __restrict__ hist)
{
    __shared__ unsigned int lh[CC * NBW];   // 40 KB

    int blk   = blockIdx.x;
    int b     = blk / (HB / BB);
    int start = blk * QPB;
    int end   = start + QPB;

    for (int i = threadIdx.x; i < CC * NBW; i += 256) lh[i] = 0u;
    __syncthreads();

    const float4* s4 = (const float4*)scores;

    for (int i0 = start + threadIdx.x; i0 < end; i0 += 1024) {
        int   ids[4];
        bool  has[4];
        float4 s[4];
        unsigned char vs[4];
        #pragma unroll
        for (int u = 0; u < 4; ++u) {
            int id = i0 + u * 256;
            has[u] = id < end;
            ids[u] = has[u] ? id : start;
        }
        #pragma unroll
        for (int u = 0; u < 4; ++u) s[u] = s4[ids[u]];
        #pragma unroll
        for (int u = 0; u < 4; ++u) vs[u] = valid[ids[u] / 20];
        #pragma unroll
        for (int u = 0; u < 4; ++u) {
            if (has[u] && vs[u]) {
                int q = ids[u] % 20;
                unsigned int* lb = &lh[(4 * q) * NBW];
                float cv[4] = {s[u].x, s[u].y, s[u].z, s[u].w};
                #pragma unroll
                for (int cl = 0; cl < 4; ++cl) {
                    float sc = cv[cl];
                    if (sc > 0.05f) {
                        int bn = min((int)(sc * 256.0f), 255);
                        atomicAdd(&lb[cl * NBW + (bn >> 1)], (bn & 1) ? 65536u : 1u);
                    }
                }
            }
        }
    }
    __syncthreads();

    unsigned int* gh = hist + (size_t)b * CC * NBW;
    for (int i = threadIdx.x; i < CC * NBW; i += 256) {
        unsigned int v = lh[i];
        if (v) atomicAdd(&gh[i], v);   // packed halves; totals < 65536 per half
    }
}

// ---------------- K3: find cut bin per (b,c), 256 bins -------------------
__global__ __launch_bounds__(256) void k_cut(
    const unsigned int* __restrict__ hist, int* __restrict__ cutbin)
{
    __shared__ unsigned int hw[NBW];
    __shared__ int best;
    int bc = blockIdx.x;
    int t  = threadIdx.x;
    if (t < NBW) hw[t] = hist[(size_t)bc * NBW + t];
    if (t == 0) best = 0;
    __syncthreads();
    unsigned int s = 0;
    for (int j = t; j < NB2; ++j)
        s += (hw[j >> 1] >> ((j & 1) * 16)) & 0xFFFFu;   // suffix sum at t
    if (s >= K_PRE) atomicMax(&best, t);
    __syncthreads();
    if (t == 0) cutbin[bc] = best;
}

// ---------------- K4: gather with LDS staging + block reservation --------
__global__ __launch_bounds__(256) void k_gather(
    const float* __restrict__ scores, const unsigned char* __restrict__ valid,
    const int* __restrict__ cutbin, unsigned int* __restrict__ cnt,
    unsigned long long* __restrict__ cand)
{
    __shared__ int lcut[CC];
    __shared__ unsigned int lcnt[CC];
    __shared__ unsigned int lbase[CC];
    __shared__ unsigned long long lkey[LBUF];   // 24 KB
    __shared__ unsigned short lcls[LBUF];       // 6 KB
    __shared__ unsigned int ltot;

    int blk   = blockIdx.x;
    int b     = blk / (HB / BB);
    int start = blk * QPB;
    int end   = start + QPB;

    if (threadIdx.x < CC) {
        lcut[threadIdx.x] = cutbin[b * CC + threadIdx.x];
        lcnt[threadIdx.x] = 0u;
    }
    if (threadIdx.x == 255) ltot = 0u;
    __syncthreads();

    const float4* s4 = (const float4*)scores;

    for (int i0 = start + threadIdx.x; i0 < end; i0 += 1024) {
        int   ids[4];
        bool  has[4];
        float4 s[4];
        unsigned char vs[4];
        #pragma unroll
        for (int u = 0; u < 4; ++u) {
            int id = i0 + u * 256;
            has[u] = id < end;
            ids[u] = has[u] ? id : start;
        }
        #pragma unroll
        for (int u = 0; u < 4; ++u) s[u] = s4[ids[u]];
        #pragma unroll
        for (int u = 0; u < 4; ++u) vs[u] = valid[ids[u] / 20];
        #pragma unroll
        for (int u = 0; u < 4; ++u) {
            if (has[u] && vs[u]) {
                int ga = ids[u] / 20;
                int c0 = 4 * (ids[u] % 20);
                unsigned long long lokey =
                    (unsigned long long)(~(unsigned int)(ga - b * AA));
                float cv[4] = {s[u].x, s[u].y, s[u].z, s[u].w};
                #pragma unroll
                for (int cl = 0; cl < 4; ++cl) {
                    float sc = cv[cl];
                    if (sc > 0.05f) {
                        int bn = min((int)(sc * 256.0f), 255);
                        int c  = c0 + cl;
                        if (bn >= lcut[c]) {
                            unsigned int p = atomicAdd(&ltot, 1u);
                            if (p < LBUF) {
                                lkey[p] = (((unsigned long long)__float_as_uint(sc)) << 32) | lokey;
                                lcls[p] = (unsigned short)c;
                                atomicAdd(&lcnt[c], 1u);
                            }
                        }
                    }
                }
            }
        }
    }
    __syncthreads();

    if (threadIdx.x < CC) {
        unsigned int nn = lcnt[threadIdx.x];
        if (nn) lbase[threadIdx.x] = atomicAdd(&cnt[b * CC + threadIdx.x], nn);
    }
    __syncthreads();

    unsigned int tot = min(ltot, (unsigned int)LBUF);
    for (unsigned int i = threadIdx.x; i < tot; i += 256) {
        int c = lcls[i];
        unsigned int pos = atomicAdd(&lbase[c], 1u);
        if (pos < CAP)
            cand[((size_t)(b * CC + c)) * CAP + pos] = lkey[i];
    }
}

// ---------------- K5: sort + NMS (register bitonic, transposed mask) ------
// n<=1024 path: key lives in a VGPR; j<64 bitonic passes via __shfl_xor
// (no barrier, no LDS array traffic); only j>=64 passes round-trip LDS
// (21 barriers total vs 55). n>1024 falls back to the LDS bitonic on 2048.
// supT fully zeroed (no uninitialized reads); greedy keep-words in registers.
__global__ __launch_bounds__(1024) void k_nms(
    const float* __restrict__ boxes, const unsigned int* __restrict__ cnt,
    const unsigned long long* __restrict__ cand, float* __restrict__ out)
{
    __shared__ unsigned long long keys[CAP];        // 16 KB
    __shared__ float4 box4[512];                    // 8 KB
    __shared__ float ar[512], scs[512];             // 4 KB
    __shared__ unsigned long long supT[512 * 8];    // 32 KB
    __shared__ unsigned long long keepsh[8];
    __shared__ int pfx[9];

    int bc = blockIdx.x;
    int b  = bc / CC;
    int n  = (int)min(cnt[bc], (unsigned int)CAP);
    int i  = threadIdx.x;

    const unsigned long long* cp = cand + (size_t)bc * CAP;

    if (n <= 1024) {
        // -------- registerized hybrid bitonic, descending --------
        unsigned long long key = (i < n) ? cp[i] : 0ull;
        for (unsigned int k = 2; k <= 1024; k <<= 1) {
            bool up = ((i & k) == 0);
            for (unsigned int j = k >> 1; j > 0; j >>= 1) {
                unsigned long long other;
                if (j >= 64) {
                    keys[i] = key;
                    __syncthreads();
                    other = keys[i ^ j];
                    __syncthreads();          // WAR guard vs next pass's write
                } else {
                    other = __shfl_xor(key, (int)j);
                }
                bool lower = ((i & j) == 0);
                bool keep_max = (lower == up);    // descending in "up" region
                bool mine_big = key > other;
                key = (keep_max == mine_big) ? key : other;
            }
        }
        keys[i] = key;
        __syncthreads();
    } else {
        // -------- fallback: full LDS bitonic on 2048 --------
        for (int t = i; t < CAP; t += 1024)
            keys[t] = (t < n) ? cp[t] : 0ull;
        for (unsigned int k = 2; k <= (unsigned int)CAP; k <<= 1) {
            for (unsigned int j = k >> 1; j > 0; j >>= 1) {
                __syncthreads();
                for (unsigned int t = i; t < (unsigned int)CAP; t += 1024) {
                    unsigned int txj = t ^ j;
                    if (txj > t) {
                        unsigned long long a = keys[t], bk = keys[txj];
                        bool up = ((t & k) == 0);
                        if (up ? (a < bk) : (a > bk)) { keys[t] = bk; keys[txj] = a; }
                    }
                }
            }
        }
        __syncthreads();
    }

    // extract top-512, gather boxes
    if (i < 512) {
        unsigned long long key = keys[i];
        bool v = (key != 0ull);
        scs[i] = v ? __uint_as_float((unsigned int)(key >> 32)) : -1.0f;
        int a = v ? (int)(~(unsigned int)key) : 0;
        float4 bb = make_float4(0.f, 0.f, 0.f, 0.f);
        if (v && i < K_PRE) bb = ((const float4*)boxes)[(size_t)b * AA + a];
        box4[i] = bb;
        ar[i] = (bb.z - bb.x) * (bb.w - bb.y);
    }
    // zero ALL of supT (defensive: no uninitialized reads possible)
    for (int t = i; t < 512 * 8; t += 1024) supT[t] = 0ull;
    __syncthreads();

    int nv = min(n, K_PRE);

    // transposed suppression masks: iw-outer so box4[i] stays in registers;
    // box4[j]/ar[j] are wave-uniform broadcasts. Only iw <= (j>>6) written.
    {
        int wave = threadIdx.x >> 6;
        int lane = threadIdx.x & 63;
        for (int iw = 0; iw < 8; ++iw) {
            int ii = iw * 64 + lane;
            float4 bi = box4[ii];
            float ia = ar[ii];
            for (int j = iw * 64 + wave; j < 512; j += 16) {
                float4 bj = box4[j];    // broadcast
                float ja = ar[j];       // broadcast
                bool p = false;
                if (ii < j && j < nv) {
                    float ltx = fmaxf(bi.x, bj.x);
                    float lty = fmaxf(bi.y, bj.y);
                    float rbx = fminf(bi.z, bj.z);
                    float rby = fminf(bi.w, bj.w);
                    float wx = fmaxf(rbx - ltx, 0.0f);
                    float wy = fmaxf(rby - lty, 0.0f);
                    float inter = wx * wy;
                    float iou = inter / fmaxf(ia + ja - inter, 1e-9f);
                    p = iou > 0.5f;
                }
                unsigned long long m = __ballot(p);
                if (lane == 0) supT[j * 8 + iw] = m;
            }
        }
    }
    __syncthreads();

    // exact greedy: word-blocked Gauss-Seidel, intra-word bounded Jacobi.
    if (threadIdx.x < 64) {
        int l = threadIdx.x;
        unsigned long long kept[8];
        #pragma unroll
        for (int w = 0; w < 8; ++w) {
            int j = w * 64 + l;
            bool vj = j < nv;
            bool ext = false;
            #pragma unroll
            for (int w2 = 0; w2 < 8; ++w2)
                if (w2 < w) ext = ext || ((supT[j * 8 + w2] & kept[w2]) != 0ull);
            unsigned long long intra = supT[j * 8 + w];   // bits i<j only
            bool base = vj && !ext;
            unsigned long long kw = __ballot(base);
            for (int r = 0; r < 64; ++r) {                // depth <= 64 => exact
                bool k2 = base && ((intra & kw) == 0ull);
                unsigned long long nkw = __ballot(k2);
                if (nkw == kw) break;
                kw = nkw;
            }
            kept[w] = kw;
        }
        if (l < 8) keepsh[l] = kept[l];
    }
    __syncthreads();

    if (threadIdx.x == 0) {
        int s = 0;
        for (int w = 0; w < 8; ++w) { pfx[w] = s; s += __popcll(keepsh[w]); }
        pfx[8] = s;
    }
    __syncthreads();

    // compaction: kept first (score order), then non-kept (score order)
    int total_kept = pfx[8];
    if (threadIdx.x < K_PRE) {
        int t = threadIdx.x;
        int w = t >> 6, bit = t & 63;
        unsigned long long kw = keepsh[w];
        bool kv = (kw >> bit) & 1ull;
        int kb = pfx[w] + __popcll(kw & ((bit == 0) ? 0ull : ((1ull << bit) - 1ull)));
        int p = kv ? kb : (total_kept + (t - kb));
        if (p < MAX_DET) {
            float* o = out + ((size_t)bc * MAX_DET + p) * 5;
            if (kv) {
                float4 bb = box4[t];
                o[0] = bb.x; o[1] = bb.y; o[2] = bb.z; o[3] = bb.w; o[4] = scs[t];
            } else {
                o[0] = 0.f; o[1] = 0.f; o[2] = 0.f; o[3] = 0.f; o[4] = -1.0f;
            }
        }
    }
}

extern "C" void kernel_launch(void* const* d_in, const int* in_sizes, int n_in,
                              void* d_out, int out_size, void* d_ws, size_t ws_size,
                              hipStream_t stream)
{
    const float* deltas  = (const float*)d_in[0];
    const float* scores  = (const float*)d_in[1];
    const float* anchors = (const float*)d_in[2];
    const int*   ih      = (const int*)d_in[3];
    const int*   iw      = (const int*)d_in[4];
    float* out = (float*)d_out;

    char* w = (char*)d_ws;
    float*              boxes  = (float*)(w + OFF_BOXES);
    unsigned char*      valid  = (unsigned char*)(w + OFF_VALID);
    unsigned int*       hist   = (unsigned int*)(w + OFF_HIST);
    unsigned int*       cnt    = (unsigned int*)(w + OFF_CNT);
    int*                cutbin = (int*)(w + OFF_CUT);
    unsigned long long* cand   = (unsigned long long*)(w + OFF_CAND);

    int g1 = (BB * AA + 255) / 256;
    k_decode<<<g1, 256, 0, stream>>>(deltas, anchors, ih, iw, boxes, valid, hist);
    k_hist<<<HB, 256, 0, stream>>>(scores, valid, hist);
    k_cut<<<BB * CC, 256, 0, stream>>>(hist, cutbin);
    k_gather<<<HB, 256, 0, stream>>>(scores, valid, cutbin, cnt, cand);
    k_nms<<<BB * CC, 1024, 0, stream>>>(boxes, cnt, cand, out);
}